// Round 3
// baseline (874.356 us; speedup 1.0000x reference)
//
#include <hip/hip_runtime.h>
#include <hip/hip_bf16.h>

// ---------------------------------------------------------------------------
// KV-cached MHA, MI355X. Inputs/outputs FP32 (per reference dtypes); internal
// compute bf16 MFMA (tolerance 0.108 permits it). No global_load_lds yet —
// staging = fp32 float4 loads -> cvt -> ds_write bf16 (m92-verified pattern).
// Shapes: B=4, TQ=1024, D=2048, H=16, Dh=128, CACHE=1024, total=2048.
// Mask tril(Tq,total): row i sees cols 0..i, i<1024 => attention touches ONLY
// cache K/V; freshly projected K/V feed the new_k/new_v outputs only.
// ---------------------------------------------------------------------------

typedef __bf16 bf16x8 __attribute__((ext_vector_type(8)));
typedef float  f32x4  __attribute__((ext_vector_type(4)));

#define MFMA16(a, b, c) __builtin_amdgcn_mfma_f32_16x16x32_bf16((a), (b), (c), 0, 0, 0)

// load 16 contiguous elements, produce two bf16x8
__device__ __forceinline__ void loadcvt16(const float* p, bf16x8& lo, bf16x8& hi) {
    const f32x4 f0 = *(const f32x4*)p;
    const f32x4 f1 = *(const f32x4*)(p + 4);
    const f32x4 f2 = *(const f32x4*)(p + 8);
    const f32x4 f3 = *(const f32x4*)(p + 12);
#pragma unroll
    for (int i = 0; i < 4; i++) {
        lo[i]     = (__bf16)f0[i];
        lo[i + 4] = (__bf16)f1[i];
        hi[i]     = (__bf16)f2[i];
        hi[i + 4] = (__bf16)f3[i];
    }
}
__device__ __forceinline__ void loadcvt16(const __bf16* p, bf16x8& lo, bf16x8& hi) {
    lo = *(const bf16x8*)p;
    hi = *(const bf16x8*)(p + 8);
}

// ---------------------------------------------------------------------------
// GEMM: C[M=4096, N=2048] = A[4096,2048] @ W[2048,2048]^T + bias
// A dtype templated (fp32 inputs or bf16 ws tensor); W/bias always fp32.
// MODE 0: C fp32 row-major [4096][2048]                  (final out proj)
// MODE 1: C bf16 scattered to ws_q [B][H][1024][128]     (Q for attention)
// MODE 2: C fp32 scattered to new_k/new_v [B][H][2048][128], t offset +1024
// ---------------------------------------------------------------------------
template <int MODE, typename AT>
__global__ __launch_bounds__(256) void gemm_bt(const AT* __restrict__ A,
                                               const float* __restrict__ W,
                                               const float* __restrict__ bias,
                                               void* __restrict__ Cv) {
    constexpr int K = 2048;
    __shared__ __bf16 aT[128 * 32];   // [row][k] row-major
    __shared__ __bf16 bT[128 * 32];

    float* Cf = (float*)Cv;
    __bf16* Cb = (__bf16*)Cv;

    const int tid = threadIdx.x;
    const int w = tid >> 6;
    const int lane = tid & 63;
    const int m0 = blockIdx.y * 128;
    const int n0 = blockIdx.x * 128;
    const int wr = w >> 1, wc = w & 1;
    const int g = lane >> 4, c = lane & 15;

    // staging map: thread owns row srow = tid>>1, 16 k-cols at shalf
    const int srow = tid >> 1, shalf = (tid & 1) * 16;
    const AT* Abase = A + (size_t)(m0 + srow) * K + shalf;
    const float* Wbase = W + (size_t)(n0 + srow) * K + shalf;

    f32x4 acc[4][4] = {};
    const int arow = wr * 64 + c;
    const int brow = wc * 64 + c;
    const int koff = g * 8;

    for (int k0 = 0; k0 < K; k0 += 32) {
        bf16x8 a_lo, a_hi, b_lo, b_hi;
        loadcvt16(Abase + k0, a_lo, a_hi);
        loadcvt16(Wbase + k0, b_lo, b_hi);
        __syncthreads();   // prior iteration's LDS reads complete
        *(bf16x8*)&aT[srow * 32 + shalf]     = a_lo;
        *(bf16x8*)&aT[srow * 32 + shalf + 8] = a_hi;
        *(bf16x8*)&bT[srow * 32 + shalf]     = b_lo;
        *(bf16x8*)&bT[srow * 32 + shalf + 8] = b_hi;
        __syncthreads();   // staging visible to all waves

        bf16x8 af[4], bfr[4];
#pragma unroll
        for (int t = 0; t < 4; t++) {
            af[t]  = *(const bf16x8*)&aT[(arow + t * 16) * 32 + koff];
            bfr[t] = *(const bf16x8*)&bT[(brow + t * 16) * 32 + koff];
        }
#pragma unroll
        for (int ti = 0; ti < 4; ti++)
#pragma unroll
            for (int tj = 0; tj < 4; tj++)
                acc[ti][tj] = MFMA16(af[ti], bfr[tj], acc[ti][tj]);
    }

    // epilogue: C/D layout col = lane&15 (n), row = (lane>>4)*4 + reg (m)
#pragma unroll
    for (int tj = 0; tj < 4; tj++) {
        const int gcol = n0 + wc * 64 + tj * 16 + c;
        const float bv = bias[gcol];
#pragma unroll
        for (int ti = 0; ti < 4; ti++) {
            const int growb = m0 + wr * 64 + ti * 16 + g * 4;
#pragma unroll
            for (int r = 0; r < 4; r++) {
                const float v = acc[ti][tj][r] + bv;
                const int row = growb + r;
                if (MODE == 0) {
                    Cf[(size_t)row * 2048 + gcol] = v;
                } else {
                    const int b = row >> 10, t = row & 1023;
                    const int h = gcol >> 7, dh = gcol & 127;
                    if (MODE == 1)
                        Cb[(((size_t)(b * 16 + h) * 1024) + t) * 128 + dh] = (__bf16)v;
                    else
                        Cf[(((size_t)(b * 16 + h) * 2048) + 1024 + t) * 128 + dh] = v;
                }
            }
        }
    }
}

// ---------------------------------------------------------------------------
// Copy cache_key/cache_value [B][1024][2048] fp32 -> new_k/new_v
// [B][H][2048][128] fp32 (cache half: t 0..1023). float4 per thread-iter.
// ---------------------------------------------------------------------------
__global__ __launch_bounds__(256) void copy_cache(const float* __restrict__ ck,
                                                  const float* __restrict__ cv,
                                                  float* __restrict__ nk,
                                                  float* __restrict__ nv) {
    const int nthreads = gridDim.x * blockDim.x;
    for (int i = blockIdx.x * blockDim.x + threadIdx.x; i < 4194304; i += nthreads) {
        const int sel = i >> 21;         // 0 = key, 1 = value
        const int j = i & 2097151;       // output chunk index (4 floats)
        const int dh4 = j & 31;
        const int t = (j >> 5) & 1023;
        const int h = (j >> 15) & 15;
        const int b = j >> 19;
        const float* src = sel ? cv : ck;
        float* dst = sel ? nv : nk;
        const size_t si = ((size_t)(b << 10) + t) * 2048 + (h << 7) + (dh4 << 2);
        const size_t di = ((size_t)b << 22) + ((size_t)h << 18) + (t << 7) + (dh4 << 2);
        *(f32x4*)&dst[di] = *(const f32x4*)&src[si];
    }
}

// ---------------------------------------------------------------------------
// Flash attention over the cache, causal (key <= qrow).
// Block = 64 q-rows (4 waves x 16 rows), K-tile = 32 keys.
// Q from ws_q bf16 [B][H][1024][128]; K/V fp32 from cache tensors (cvt on
// staging). Output -> ws_attn bf16 [4096][2048] (head-interleaved cols).
// ---------------------------------------------------------------------------
__global__ __launch_bounds__(256) void attn_k(const __bf16* __restrict__ Qw,
                                              const float* __restrict__ cK,
                                              const float* __restrict__ cV,
                                              __bf16* __restrict__ O) {
    __shared__ __bf16 Kt[32 * 128];   // [key][dh]
    __shared__ __bf16 Vt[128 * 32];   // [dh][key] (transposed for B-frag reads)
    __shared__ __bf16 Pw[4][16 * 32]; // per-wave P round-trip

    const int tid = threadIdx.x;
    const int w = tid >> 6;
    const int lane = tid & 63;
    const int g = lane >> 4, c = lane & 15;
    const int b = blockIdx.z, h = blockIdx.y, q0 = blockIdx.x * 64;
    const float inv_scale = 0.08838834764831845f; // 1/sqrt(128)

    // Q A-fragments (A[m=lane&15][k=(lane>>4)*8+j]), held for the whole block
    const __bf16* qbase = Qw + (((size_t)(b * 16 + h) * 1024) + q0 + w * 16) * 128;
    bf16x8 qf[4];
#pragma unroll
    for (int dc = 0; dc < 4; dc++)
        qf[dc] = *(const bf16x8*)&qbase[c * 128 + dc * 32 + g * 8];

    f32x4 accO[8] = {};
    float m_run[4], l_run[4];
#pragma unroll
    for (int r = 0; r < 4; r++) { m_run[r] = -1e30f; l_run[r] = 0.0f; }

    const int trips = q0 / 32 + 2; // covers keys 0 .. q0+63
    const float* kb = cK + (size_t)b * 1024 * 2048 + h * 128;
    const float* vb = cV + (size_t)b * 1024 * 2048 + h * 128;

    // staging map: thread owns key skey = tid>>3, 16 dh at sdh
    const int skey = tid >> 3, sdh = (tid & 7) * 16;

    for (int kt = 0; kt < trips; kt++) {
        const int k0 = kt * 32;
        bf16x8 k_lo, k_hi, v_lo, v_hi;
        loadcvt16(kb + (size_t)(k0 + skey) * 2048 + sdh, k_lo, k_hi);
        loadcvt16(vb + (size_t)(k0 + skey) * 2048 + sdh, v_lo, v_hi);
        __syncthreads();   // prior iteration's Kt/Vt reads complete
        *(bf16x8*)&Kt[skey * 128 + sdh]     = k_lo;
        *(bf16x8*)&Kt[skey * 128 + sdh + 8] = k_hi;
#pragma unroll
        for (int j = 0; j < 8; j++) {
            Vt[(sdh + j) * 32 + skey]     = v_lo[j];
            Vt[(sdh + 8 + j) * 32 + skey] = v_hi[j];
        }
        __syncthreads();   // staging visible

        // S = Q @ K^T  (two 16-col tiles over this 32-key tile)
        f32x4 s_acc[2] = {};
#pragma unroll
        for (int nt = 0; nt < 2; nt++)
#pragma unroll
            for (int dc = 0; dc < 4; dc++) {
                bf16x8 kf = *(const bf16x8*)&Kt[(nt * 16 + c) * 128 + dc * 32 + g * 8];
                s_acc[nt] = MFMA16(qf[dc], kf, s_acc[nt]);
            }

        // mask + online softmax (this lane holds rows g*4+r, cols c / c+16)
        float p[2][4], alpha[4];
#pragma unroll
        for (int r = 0; r < 4; r++) {
            const int qrow = q0 + w * 16 + g * 4 + r;
            float s0 = (k0 + c      <= qrow) ? s_acc[0][r] * inv_scale : -1e30f;
            float s1 = (k0 + 16 + c <= qrow) ? s_acc[1][r] * inv_scale : -1e30f;
            float rm = fmaxf(s0, s1);
            rm = fmaxf(rm, __shfl_xor(rm, 1));
            rm = fmaxf(rm, __shfl_xor(rm, 2));
            rm = fmaxf(rm, __shfl_xor(rm, 4));
            rm = fmaxf(rm, __shfl_xor(rm, 8));
            const float mnew = fmaxf(m_run[r], rm);
            alpha[r] = __expf(m_run[r] - mnew);
            const float p0 = __expf(s0 - mnew);
            const float p1 = __expf(s1 - mnew);
            p[0][r] = p0; p[1][r] = p1;
            float ps = p0 + p1;
            ps += __shfl_xor(ps, 1);
            ps += __shfl_xor(ps, 2);
            ps += __shfl_xor(ps, 4);
            ps += __shfl_xor(ps, 8);
            l_run[r] = alpha[r] * l_run[r] + ps;
            m_run[r] = mnew;
        }
#pragma unroll
        for (int nt2 = 0; nt2 < 8; nt2++)
#pragma unroll
            for (int r = 0; r < 4; r++)
                accO[nt2][r] *= alpha[r];

        // P -> LDS (C-layout write: [qrow][key]), re-read as A-fragment
#pragma unroll
        for (int nt = 0; nt < 2; nt++)
#pragma unroll
            for (int r = 0; r < 4; r++)
                Pw[w][(g * 4 + r) * 32 + nt * 16 + c] = (__bf16)p[nt][r];
        __syncthreads();

        const bf16x8 pf = *(const bf16x8*)&Pw[w][c * 32 + g * 8];
#pragma unroll
        for (int nt2 = 0; nt2 < 8; nt2++) {
            bf16x8 vf = *(const bf16x8*)&Vt[(nt2 * 16 + c) * 32 + g * 8];
            accO[nt2] = MFMA16(pf, vf, accO[nt2]);
        }
    }

    // epilogue: normalize and store bf16 to ws_attn [4096][2048]
#pragma unroll
    for (int nt2 = 0; nt2 < 8; nt2++)
#pragma unroll
        for (int r = 0; r < 4; r++) {
            const float v = accO[nt2][r] / l_run[r];
            const int row = b * 1024 + q0 + w * 16 + g * 4 + r;
            const int col = h * 128 + nt2 * 16 + c;
            O[(size_t)row * 2048 + col] = (__bf16)v;
        }
}

// ---------------------------------------------------------------------------
extern "C" void kernel_launch(void* const* d_in, const int* in_sizes, int n_in,
                              void* d_out, int out_size, void* d_ws, size_t ws_size,
                              hipStream_t stream) {
    const float* query       = (const float*)d_in[0];
    const float* key         = (const float*)d_in[1];
    const float* value       = (const float*)d_in[2];
    const float* cache_key   = (const float*)d_in[3];
    const float* cache_value = (const float*)d_in[4];
    const float* Wq = (const float*)d_in[5];
    const float* bq = (const float*)d_in[6];
    const float* Wk = (const float*)d_in[7];
    const float* bk = (const float*)d_in[8];
    const float* Wv = (const float*)d_in[9];
    const float* bv = (const float*)d_in[10];
    const float* Wo = (const float*)d_in[11];
    const float* bo = (const float*)d_in[12];

    float* out   = (float*)d_out;              // [4096][2048] fp32
    float* new_k = out + 8388608;              // [B][H][2048][128] fp32
    float* new_v = out + 25165824;

    __bf16* ws_q    = (__bf16*)d_ws;           // [B][H][1024][128] bf16, 16.8 MB
    __bf16* ws_attn = ws_q + 8388608;          // [4096][2048] bf16, 16.8 MB

    const dim3 gemm_grid(16, 32);              // N/128 x M/128

    copy_cache<<<4096, 256, 0, stream>>>(cache_key, cache_value, new_k, new_v);
    gemm_bt<1, float><<<gemm_grid, 256, 0, stream>>>(query, Wq, bq, ws_q);
    gemm_bt<2, float><<<gemm_grid, 256, 0, stream>>>(key,   Wk, bk, new_k);
    gemm_bt<2, float><<<gemm_grid, 256, 0, stream>>>(value, Wv, bv, new_v);
    attn_k<<<dim3(16, 16, 4), 256, 0, stream>>>(ws_q, cache_key, cache_value, ws_attn);
    gemm_bt<0, __bf16><<<gemm_grid, 256, 0, stream>>>(ws_attn, Wo, bo, out);
}